// Round 20
// baseline (221.158 us; speedup 1.0000x reference)
//
#include <hip/hip_runtime.h>
#include <hip/hip_bf16.h>
#include <float.h>

// Problem constants
constexpr int Bc = 4;
constexpr int Lc = 2048;
constexpr int Dc = 512;
constexpr int Hc = 8;
constexpr int Ec = 64;
constexpr int Sc = 40;   // sample_k
constexpr int Uc = 40;   // u_q (top-k queries)
constexpr int LEc = Lc * Ec;      // 131072
constexpr int BHc = Bc * Hc;      // 32
constexpr int Mrows = Bc * Lc;    // 8192 rows per GEMM

typedef __attribute__((ext_vector_type(8))) short s16x8;
typedef __attribute__((ext_vector_type(4))) float f32x4;
typedef unsigned int u32;

// round-to-nearest-even f32 -> bf16 (bit pattern in a short)
__device__ __forceinline__ short f2bf(float x) {
    unsigned u = __float_as_uint(x);
    unsigned r = (u + 0x7fffu + ((u >> 16) & 1u)) >> 16;
    return (short)r;
}
__device__ __forceinline__ float bf2f(short s) {
    return __uint_as_float(((unsigned)(unsigned short)s) << 16);
}
__device__ __forceinline__ uint4 pack8(const short* s) {
    uint4 r;
    r.x = (unsigned)(unsigned short)s[0] | ((unsigned)(unsigned short)s[1] << 16);
    r.y = (unsigned)(unsigned short)s[2] | ((unsigned)(unsigned short)s[3] << 16);
    r.z = (unsigned)(unsigned short)s[4] | ((unsigned)(unsigned short)s[5] << 16);
    r.w = (unsigned)(unsigned short)s[6] | ((unsigned)(unsigned short)s[7] << 16);
    return r;
}

// direct global->LDS DMA, 16 B per lane (dest = wave-uniform base + lane*16)
__device__ __forceinline__ void gld_lds16(const short* g, short* l) {
    __builtin_amdgcn_global_load_lds(
        (const __attribute__((address_space(1))) u32*)g,
        (__attribute__((address_space(3))) u32*)l, 16, 0, 0);
}

// ---------------------------------------------------------------------------
// Kernel 0a: split q,k -> (hi,lo) bf16; v -> hi bf16.
// Groups XOR-swizzled within each 128-B row block (see gemm read side).
// ---------------------------------------------------------------------------
__global__ __launch_bounds__(256) void split_inputs(
    const float* __restrict__ q, const float* __restrict__ k, const float* __restrict__ v,
    short* __restrict__ qhi, short* __restrict__ qlo,
    short* __restrict__ khi, short* __restrict__ klo, short* __restrict__ vhi)
{
    int tid = blockIdx.x * 256 + threadIdx.x;
    int z   = tid >> 19;                  // 2^19 groups (of 8 floats) per tensor
    int g8  = tid & ((1 << 19) - 1);
    int row = g8 >> 6;                    // 64 groups per 512-float row
    int gin = g8 & 63;
    int slot = (gin & ~7) | ((gin ^ row) & 7);
    const float* src = (z == 0) ? q : (z == 1) ? k : v;
    const float4* s4 = (const float4*)src + (size_t)g8 * 2;
    float4 d0 = s4[0], d1 = s4[1];
    float f[8] = {d0.x, d0.y, d0.z, d0.w, d1.x, d1.y, d1.z, d1.w};
    short hs[8], ls[8];
    #pragma unroll
    for (int i = 0; i < 8; ++i) {
        hs[i] = f2bf(f[i]);
        ls[i] = f2bf(f[i] - bf2f(hs[i]));
    }
    size_t off = (size_t)row * 512 + slot * 8;
    if (z == 2) { *(uint4*)(vhi + off) = pack8(hs); return; }
    if (z == 0) { *(uint4*)(qhi + off) = pack8(hs); *(uint4*)(qlo + off) = pack8(ls); }
    else        { *(uint4*)(khi + off) = pack8(hs); *(uint4*)(klo + off) = pack8(ls); }
}

// ---------------------------------------------------------------------------
// Kernel 0b: W prep — transpose + K-extended split layout, XOR-swizzled groups.
// ---------------------------------------------------------------------------
__global__ __launch_bounds__(256) void wprep(
    const float* __restrict__ Wq, const float* __restrict__ Wk,
    const float* __restrict__ Wv,
    short* __restrict__ Bq, short* __restrict__ Bk, short* __restrict__ Bv)
{
    __shared__ float tile[64][65];
    int z = blockIdx.z;
    const float* W = (z == 0) ? Wq : (z == 1) ? Wk : Wv;
    int k0 = blockIdx.x * 64, n0 = blockIdx.y * 64;
    int t = threadIdx.x;
    #pragma unroll
    for (int i = 0; i < 4; ++i) {
        int c = i * 256 + t, row = c >> 4, qq = c & 15;
        float4 d = *(const float4*)(W + (size_t)(k0 + row) * Dc + n0 + qq * 4);
        tile[row][qq * 4 + 0] = d.x; tile[row][qq * 4 + 1] = d.y;
        tile[row][qq * 4 + 2] = d.z; tile[row][qq * 4 + 3] = d.w;
    }
    __syncthreads();
    int n = t >> 2, ks = (t & 3) * 16;
    int nglob = n0 + n;
    short hs[16], ls[16];
    #pragma unroll
    for (int j = 0; j < 16; ++j) {
        float x = tile[ks + j][n];
        short h = f2bf(x);
        hs[j] = h;
        ls[j] = f2bf(x - bf2f(h));
    }
    int G0 = (k0 + ks) >> 3;
    int s0 = (G0 & ~7) | ((G0 ^ nglob) & 7);
    int s1 = ((G0 + 1) & ~7) | (((G0 + 1) ^ nglob) & 7);
    if (z < 2) {
        short* Bx = (z == 0) ? Bq : Bk;
        size_t rb = (size_t)nglob * 1536;
        *(uint4*)(Bx + rb + s0 * 8)        = pack8(hs);
        *(uint4*)(Bx + rb + s1 * 8)        = pack8(hs + 8);
        *(uint4*)(Bx + rb + 512 + s0 * 8)  = pack8(ls);
        *(uint4*)(Bx + rb + 512 + s1 * 8)  = pack8(ls + 8);
        *(uint4*)(Bx + rb + 1024 + s0 * 8) = pack8(hs);
        *(uint4*)(Bx + rb + 1024 + s1 * 8) = pack8(hs + 8);
    } else {
        size_t rb = (size_t)nglob * 512;
        *(uint4*)(Bv + rb + s0 * 8) = pack8(hs);
        *(uint4*)(Bv + rb + s1 * 8) = pack8(hs + 8);
    }
}

// ---------------------------------------------------------------------------
// Kernel 1: projection GEMMs, m97 structure + swizzled LDS (R15 config:
// 128x128 block, 4 waves, 64x64 per wave — the 2-phase local optimum).
// ---------------------------------------------------------------------------
__global__ __launch_bounds__(256) void gemm_mfma(
    const short* __restrict__ qhi, const short* __restrict__ qlo,
    const short* __restrict__ khi, const short* __restrict__ klo,
    const short* __restrict__ vhi,
    const short* __restrict__ Bq, const short* __restrict__ Bk,
    const short* __restrict__ Bv,
    float* __restrict__ qp, float* __restrict__ kp, float* __restrict__ vp)
{
    int z = blockIdx.z;
    const short* Ahi = (z == 0) ? qhi : (z == 1) ? khi : vhi;
    const short* Alo = (z == 0) ? qlo : (z == 1) ? klo : vhi;  // unused for z==2
    const short* Bx  = (z == 0) ? Bq  : (z == 1) ? Bk  : Bv;
    float* O = (z == 0) ? qp : (z == 1) ? kp : vp;
    const int Ktot = (z == 2) ? 512 : 1536;
    const int nseg = (z == 2) ? 1 : 3;

    __shared__ short As[128 * 64];
    __shared__ short Bs[128 * 64];

    const int t = threadIdx.x;
    const int lane = t & 63, w = t >> 6;
    const int wm = w >> 1, wn = w & 1;
    const int row0 = blockIdx.x * 128, col0 = blockIdx.y * 128;
    const int kg = lane >> 4, fr = lane & 15;
    const int sx = fr & 7;                               // read-slot XOR
    const int lrow = lane >> 3, lcol = (lane & 7) * 8;   // staging: 8 rows x 128B

    f32x4 acc[4][4];
    #pragma unroll
    for (int i = 0; i < 4; ++i)
        #pragma unroll
        for (int j = 0; j < 4; ++j)
            acc[i][j] = (f32x4){0.f, 0.f, 0.f, 0.f};

    for (int seg = 0; seg < nseg; ++seg) {
        const short* Asrc = ((seg == 2) ? Alo : Ahi)
                          + (size_t)(row0 + lrow) * 512 + lcol;
        const short* Bsrc = Bx + (size_t)(col0 + lrow) * Ktot + seg * 512 + lcol;
        for (int ks = 0; ks < 512; ks += 64) {
            __syncthreads();
            #pragma unroll
            for (int i = 0; i < 4; ++i) {
                int r = w * 32 + i * 8;
                gld_lds16(Asrc + (size_t)r * 512 + ks, &As[r * 64]);
            }
            #pragma unroll
            for (int i = 0; i < 4; ++i) {
                int r = w * 32 + i * 8;
                gld_lds16(Bsrc + (size_t)r * Ktot + ks, &Bs[r * 64]);
            }
            __syncthreads();

            #pragma unroll
            for (int kk = 0; kk < 2; ++kk) {
                const int slot = ((kk * 4 + kg) ^ sx) * 8;
                s16x8 a[4];
                #pragma unroll
                for (int mi = 0; mi < 4; ++mi)
                    a[mi] = *(const s16x8*)&As[(wm * 64 + mi * 16 + fr) * 64 + slot];
                #pragma unroll
                for (int ni = 0; ni < 4; ++ni) {
                    s16x8 b = *(const s16x8*)&Bs[(wn * 64 + ni * 16 + fr) * 64 + slot];
                    #pragma unroll
                    for (int mi = 0; mi < 4; ++mi)
                        acc[mi][ni] = __builtin_amdgcn_mfma_f32_16x16x32_bf16(a[mi], b, acc[mi][ni], 0, 0, 0);
                }
            }
        }
    }

    // epilogue: C/D layout col=lane&15, row=(lane>>4)*4+reg
    #pragma unroll
    for (int mi = 0; mi < 4; ++mi) {
        #pragma unroll
        for (int ni = 0; ni < 4; ++ni) {
            int row = row0 + wm * 64 + mi * 16 + (lane >> 4) * 4;
            int col = col0 + wn * 64 + ni * 16 + (lane & 15);
            #pragma unroll
            for (int r4 = 0; r4 < 4; ++r4)
                O[(size_t)(row + r4) * Dc + col] = acc[mi][ni][r4];
        }
    }
}

// ---------------------------------------------------------------------------
// Kernel 2: sampled scores -> m[bh, l] = max_s(dot) - sum_s(dot)/L
// GROUP-COALESCED gather + XCD-aware swizzle.
// ---------------------------------------------------------------------------
__global__ __launch_bounds__(256) void compute_m(
    const float* __restrict__ qp, const float* __restrict__ kp,
    const int* __restrict__ ksi, float* __restrict__ m_out)
{
    __shared__ float qsh[4][Ec];
    __shared__ int   jsh[4][Sc];
    int w    = threadIdx.x >> 6;
    int lane = threadIdx.x & 63;
    int xcd  = blockIdx.x & 7;
    int i    = blockIdx.x >> 3;
    int bh   = (xcd << 2) | (i >> 9);
    int l    = (i & 511) * 4 + w;
    const float* kbase = kp + (size_t)bh * LEc;

    qsh[w][lane] = qp[(size_t)bh * LEc + l * Ec + lane];
    if (lane < Sc) jsh[w][lane] = ksi[l * Sc + lane];
    __syncthreads();

    const int g = lane >> 2;
    const int c = lane & 3;

    float mx = -FLT_MAX, sm = 0.f;
    #pragma unroll
    for (int it = 0; it < 3; ++it) {
        int s = it * 16 + g;
        bool valid = (s < Sc);
        float partial = 0.f;
        if (valid) {
            int j = jsh[w][s];
            const float4* krow = (const float4*)(kbase + (size_t)j * Ec);
            #pragma unroll
            for (int ii = 0; ii < 4; ++ii) {
                float4 kv = krow[ii * 4 + c];
                float4 qv = *(const float4*)&qsh[w][ii * 16 + c * 4];
                partial += kv.x * qv.x + kv.y * qv.y + kv.z * qv.z + kv.w * qv.w;
            }
        }
        partial += __shfl_xor(partial, 1);
        partial += __shfl_xor(partial, 2);
        float vmax = valid ? partial : -FLT_MAX;
        float vsum = (valid && c == 0) ? partial : 0.f;
        #pragma unroll
        for (int o = 4; o < 64; o <<= 1) {
            vmax = fmaxf(vmax, __shfl_xor(vmax, o));
            vsum += __shfl_xor(vsum, o);
        }
        mx = fmaxf(mx, vmax);
        sm += vsum;
    }
    if (lane == 0) m_out[bh * Lc + l] = mx - sm * (1.0f / Lc);
}

// ---------------------------------------------------------------------------
// Kernel 3: top-40 via SHUFFLE-BROADCAST ranking — no LDS, no atomics, no
// memset, zero memory ops in the hot loop. Each lane owns vi; 32 chunks of
// {1 coalesced global load + 64 register broadcasts x 2 compares}.
// rank = #{v_j > v_i} + #{j<i: v_j == v_i} (jax.lax.top_k order); ranks of
// selected elements are unique in [0,40) -> direct slot write.
// ---------------------------------------------------------------------------
__global__ __launch_bounds__(256) void topk40(
    const float* __restrict__ m_in, int* __restrict__ mtop)
{
    int bh = blockIdx.x >> 3, seg = blockIdx.x & 7;
    int t = threadIdx.x, lane = t & 63;
    const float* base = m_in + (size_t)bh * Lc;
    int myi = seg * 256 + t;
    float vi = base[myi];
    int rgt = 0, rge = 0;
    for (int c = 0; c < Lc / 64; ++c) {
        float vc = base[c * 64 + lane];       // coalesced 256B/wave, L2-hit
        #pragma unroll
        for (int b = 0; b < 64; ++b) {
            float vb = __shfl(vc, b);          // register broadcast
            rgt += (vb > vi);
            rge += (vb >= vi);
        }
    }
    int rank;
    if (rge - rgt == 1) {                     // value unique -> rank = rgt
        rank = rgt;
    } else {                                   // duplicates: positional count
        int req = 0;
        for (int j = 0; j < myi; ++j) req += (base[j] == vi);
        rank = rgt + req;
    }
    if (rank < Uc) mtop[bh * Uc + rank] = myi;
}

// ---------------------------------------------------------------------------
// Kernels 4-6: chunked inclusive cumsum of vp along l, per (bh, e) column.
// ---------------------------------------------------------------------------
constexpr int CH = 64;  // chunks
constexpr int CR = 32;  // rows per chunk

__global__ __launch_bounds__(64) void cumsum_p1(
    const float* __restrict__ vp, float* __restrict__ psum)
{
    int bid = blockIdx.x;
    int e = threadIdx.x;
    int bh = bid >> 6, ch = bid & 63;
    const float* base = vp + (size_t)bh * LEc + (ch * CR) * Ec + e;
    float s = 0.f;
    #pragma unroll 8
    for (int r = 0; r < CR; ++r) s += base[r * Ec];
    psum[(size_t)bid * Ec + e] = s;
}

__global__ __launch_bounds__(64) void cumsum_p2(float* __restrict__ psum)
{
    int bh = blockIdx.x;
    int e = threadIdx.x;
    float off = 0.f;
    for (int c = 0; c < CH; ++c) {
        size_t idx = (size_t)(bh * CH + c) * Ec + e;
        float tv = psum[idx];
        psum[idx] = off;
        off += tv;
    }
}

__global__ __launch_bounds__(64) void cumsum_p3(
    const float* __restrict__ vp, const float* __restrict__ psum,
    float* __restrict__ out)
{
    int bid = blockIdx.x;
    int e = threadIdx.x;
    int bh = bid >> 6, ch = bid & 63;
    const float* base = vp  + (size_t)bh * LEc + (ch * CR) * Ec + e;
    float*       ob   = out + (size_t)bh * LEc + (ch * CR) * Ec + e;
    float run = psum[(size_t)bid * Ec + e];
    #pragma unroll 8
    for (int r = 0; r < CR; ++r) { run += base[r * Ec]; ob[r * Ec] = run; }
}

// ---------------------------------------------------------------------------
// Kernel 7a: chunked attention partials with u-reuse; fixed softmax base 0;
// balanced chunk pairing (ch, 15-ch); transposed p_t for b128 PV reads.
// ---------------------------------------------------------------------------
constexpr int ACH = 16;     // attn chunks
constexpr int AROWS = 128;  // rows per chunk

__global__ __launch_bounds__(512) void attn_partial(
    const float* __restrict__ qp, const float* __restrict__ kp,
    const float* __restrict__ vp, const int* __restrict__ mtop,
    float* __restrict__ pl, float* __restrict__ pacc)
{
    __shared__ float Kt[64][68];     // stride 68: float4-aligned rows
    __shared__ float Vt[64][68];
    __shared__ float qsh[40][64];
    __shared__ float p_t[40][68];    // p transposed: [u][row], 16B-aligned rows
    __shared__ int   lsel_sh[40];

    int half = blockIdx.x >> 8, sub = blockIdx.x & 255;
    int bh = sub & 31;
    int ch = half ? (15 - (sub >> 5)) : (sub >> 5);
    int t = threadIdx.x, w = t >> 6, lane = t & 63;
    const float* kb = kp + (size_t)bh * LEc;
    const float* vb = vp + (size_t)bh * LEc;

    if (t < Uc) lsel_sh[t] = mtop[bh * Uc + t];
    __syncthreads();
    for (int i = t; i < Uc * Ec; i += 512) {
        int u = i >> 6, e = i & 63;
        qsh[u][e] = qp[(size_t)bh * LEc + lsel_sh[u] * Ec + e];
    }

    const int u0 = w * 5;
    float acc[5]  = {0.f, 0.f, 0.f, 0.f, 0.f};
    float lreg[5] = {0.f, 0.f, 0.f, 0.f, 0.f};

    for (int tt = 0; tt < AROWS / 64; ++tt) {
        int l0 = ch * AROWS + tt * 64;
        __syncthreads();   // prev-tile reads done (and qsh written, first iter)
        #pragma unroll
        for (int i = 0; i < 2; ++i) {
            int f = i * 512 + t, row = f >> 4, cg = f & 15;
            *(float4*)&Kt[row][cg * 4] = *(const float4*)(kb + (size_t)(l0 + row) * Ec + cg * 4);
            *(float4*)&Vt[row][cg * 4] = *(const float4*)(vb + (size_t)(l0 + row) * Ec + cg * 4);
        }
        __syncthreads();

        int gl = l0 + lane;
        float4 kr[16];
        #pragma unroll
        for (int i = 0; i < 16; ++i) kr[i] = *(const float4*)&Kt[lane][i * 4];

        bool act[5];
        #pragma unroll
        for (int j = 0; j < 5; ++j) {
            int u = u0 + j, ls = lsel_sh[u];
            act[j] = (l0 <= ls);            // wave-uniform
            if (!act[j]) continue;
            float p = 0.f;
            if (gl <= ls) {
                float dot = 0.f;
                #pragma unroll
                for (int i = 0; i < 16; ++i) {
                    float4 qv = *(const float4*)&qsh[u][i * 4];   // broadcast
                    dot += kr[i].x * qv.x + kr[i].y * qv.y + kr[i].z * qv.z + kr[i].w * qv.w;
                }
                p = __expf(dot * 0.125f);   // fixed base 0
            }
            p_t[u][lane] = p;               // consecutive lanes -> conflict-free
            float ps = p;
            #pragma unroll
            for (int o = 1; o < 64; o <<= 1) ps += __shfl_xor(ps, o);
            lreg[j] += ps;
        }

        // PV: lane = e; Vt scalar reads shared across u, p via b128 broadcast.
        #pragma unroll
        for (int i = 0; i < 16; ++i) {
            float v0 = Vt[i * 4 + 0][lane];
            float v1 = Vt[i * 4 + 1][lane];
            float v2 = Vt[i * 4 + 2][lane];
            float v3 = Vt[i * 4 + 3][lane];
            #pragma unroll
            for (int j = 0; j < 5; ++j) {
                if (!act[j]) continue;
                float4 pv = *(const float4*)&p_t[u0 + j][i * 4];   // broadcast
                acc[j] += pv.x * v0 + pv.y * v1 + pv.z * v2 + pv.w * v3;
            }
        }
    }

    #pragma unroll
    for (int j = 0; j < 5; ++j) {
        size_t idx = ((size_t)bh * ACH + ch) * Uc + u0 + j;
        if (lane == 0) pl[idx] = lreg[j];
        pacc[idx * Ec + lane] = acc[j];
    }
}

// ---------------------------------------------------------------------------
// Kernel 7b: combine (plain sums — fixed base 0); write out row.
// ---------------------------------------------------------------------------
__global__ __launch_bounds__(256) void attn_combine(
    const float* __restrict__ pl, const float* __restrict__ pacc,
    const int* __restrict__ mtop, float* __restrict__ out)
{
    int wid = blockIdx.x * 4 + (threadIdx.x >> 6);
    int lane = threadIdx.x & 63;
    int bh = wid / Uc, u = wid % Uc;
    float l = 0.f, a = 0.f;
    for (int i = 0; i < ACH; ++i) {
        size_t idx = ((size_t)bh * ACH + i) * Uc + u;
        l += pl[idx];
        a += pacc[idx * Ec + lane];
    }
    int lsel = mtop[bh * Uc + u];
    out[(size_t)bh * LEc + lsel * Ec + lane] = a / l;
}

// ---------------------------------------------------------------------------
extern "C" void kernel_launch(void* const* d_in, const int* in_sizes, int n_in,
                              void* d_out, int out_size, void* d_ws, size_t ws_size,
                              hipStream_t stream)
{
    const float* q   = (const float*)d_in[0];
    const float* k   = (const float*)d_in[1];
    const float* v   = (const float*)d_in[2];
    const float* Wq  = (const float*)d_in[3];
    const float* Wk  = (const float*)d_in[4];
    const float* Wv  = (const float*)d_in[5];
    const int*   ksi = (const int*)d_in[6];
    float* out = (float*)d_out;

    // workspace layout
    float* wsf  = (float*)d_ws;
    float* qp   = wsf;                            // 4,194,304 f
    float* kp   = qp + (size_t)Mrows * Dc;        // 4,194,304 f
    float* vp   = kp + (size_t)Mrows * Dc;        // 4,194,304 f
    float* psum = vp + (size_t)Mrows * Dc;        // 131,072 f
    float* m_ws = psum + (size_t)BHc * CH * Ec;   // 65,536 f
    int*   mtop = (int*)(m_ws + (size_t)BHc * Lc);      // 1,280 i
    short* qhi = (short*)(mtop + BHc * Uc);
    short* qlo = qhi + (size_t)Mrows * Dc;
    short* khi = qlo + (size_t)Mrows * Dc;
    short* klo = khi + (size_t)Mrows * Dc;
    short* vhi = klo + (size_t)Mrows * Dc;
    short* Bq  = vhi + (size_t)Mrows * Dc;        // 512*1536
    short* Bk  = Bq + (size_t)Dc * 1536;          // 512*1536
    short* Bv  = Bk + (size_t)Dc * 1536;          // 512*512
    float* pl  = (float*)(Bv + (size_t)Dc * 512); // 32*16*40
    float* pacc = pl + (size_t)BHc * ACH * Uc;    // 32*16*40*64

    split_inputs<<<3 * (Mrows * Dc / 8) / 256, 256, 0, stream>>>(
        q, k, v, qhi, qlo, khi, klo, vhi);
    wprep<<<dim3(8, 8, 3), 256, 0, stream>>>(Wq, Wk, Wv, Bq, Bk, Bv);

    dim3 g1(Mrows / 128, Dc / 128, 3);
    gemm_mfma<<<g1, 256, 0, stream>>>(qhi, qlo, khi, klo, vhi, Bq, Bk, Bv,
                                      qp, kp, vp);

    compute_m<<<(BHc * Lc) / 4, 256, 0, stream>>>(qp, kp, ksi, m_ws);

    topk40<<<BHc * 8, 256, 0, stream>>>(m_ws, mtop);

    attn_partial<<<BHc * ACH, 512, 0, stream>>>(qp, kp, vp, mtop, pl, pacc);

    cumsum_p1<<<BHc * CH, 64, 0, stream>>>(vp, psum);
    cumsum_p2<<<BHc, 64, 0, stream>>>(psum);
    cumsum_p3<<<BHc * CH, 64, 0, stream>>>(vp, psum, out);

    attn_combine<<<BHc * Uc / 4, 256, 0, stream>>>(pl, pacc, mtop, out);
}

// Round 21
// 151.411 us; speedup vs baseline: 1.4606x; 1.4606x over previous
//
#include <hip/hip_runtime.h>
#include <hip/hip_bf16.h>
#include <float.h>

// Problem constants
constexpr int Bc = 4;
constexpr int Lc = 2048;
constexpr int Dc = 512;
constexpr int Hc = 8;
constexpr int Ec = 64;
constexpr int Sc = 40;   // sample_k
constexpr int Uc = 40;   // u_q (top-k queries)
constexpr int LEc = Lc * Ec;      // 131072
constexpr int BHc = Bc * Hc;      // 32
constexpr int Mrows = Bc * Lc;    // 8192 rows per GEMM

typedef __attribute__((ext_vector_type(8))) short s16x8;
typedef __attribute__((ext_vector_type(4))) float f32x4;
typedef unsigned int u32;

// round-to-nearest-even f32 -> bf16 (bit pattern in a short)
__device__ __forceinline__ short f2bf(float x) {
    unsigned u = __float_as_uint(x);
    unsigned r = (u + 0x7fffu + ((u >> 16) & 1u)) >> 16;
    return (short)r;
}
__device__ __forceinline__ float bf2f(short s) {
    return __uint_as_float(((unsigned)(unsigned short)s) << 16);
}
__device__ __forceinline__ uint4 pack8(const short* s) {
    uint4 r;
    r.x = (unsigned)(unsigned short)s[0] | ((unsigned)(unsigned short)s[1] << 16);
    r.y = (unsigned)(unsigned short)s[2] | ((unsigned)(unsigned short)s[3] << 16);
    r.z = (unsigned)(unsigned short)s[4] | ((unsigned)(unsigned short)s[5] << 16);
    r.w = (unsigned)(unsigned short)s[6] | ((unsigned)(unsigned short)s[7] << 16);
    return r;
}

// direct global->LDS DMA, 16 B per lane (dest = wave-uniform base + lane*16)
__device__ __forceinline__ void gld_lds16(const short* g, short* l) {
    __builtin_amdgcn_global_load_lds(
        (const __attribute__((address_space(1))) u32*)g,
        (__attribute__((address_space(3))) u32*)l, 16, 0, 0);
}

// ---------------------------------------------------------------------------
// Kernel 0a: split q,k -> (hi,lo) bf16; v -> hi bf16.
// Groups XOR-swizzled within each 128-B row block (see gemm read side).
// Also zeroes the 32-int topk counter (block 0) — replaces the pathological
// 41 us fillBufferAligned dispatch seen in R18.
// ---------------------------------------------------------------------------
__global__ __launch_bounds__(256) void split_inputs(
    const float* __restrict__ q, const float* __restrict__ k, const float* __restrict__ v,
    short* __restrict__ qhi, short* __restrict__ qlo,
    short* __restrict__ khi, short* __restrict__ klo, short* __restrict__ vhi,
    int* __restrict__ cnt)
{
    int tid = blockIdx.x * 256 + threadIdx.x;
    if (tid < BHc) cnt[tid] = 0;          // stream-serialized before topk40
    int z   = tid >> 19;                  // 2^19 groups (of 8 floats) per tensor
    int g8  = tid & ((1 << 19) - 1);
    int row = g8 >> 6;                    // 64 groups per 512-float row
    int gin = g8 & 63;
    int slot = (gin & ~7) | ((gin ^ row) & 7);
    const float* src = (z == 0) ? q : (z == 1) ? k : v;
    const float4* s4 = (const float4*)src + (size_t)g8 * 2;
    float4 d0 = s4[0], d1 = s4[1];
    float f[8] = {d0.x, d0.y, d0.z, d0.w, d1.x, d1.y, d1.z, d1.w};
    short hs[8], ls[8];
    #pragma unroll
    for (int i = 0; i < 8; ++i) {
        hs[i] = f2bf(f[i]);
        ls[i] = f2bf(f[i] - bf2f(hs[i]));
    }
    size_t off = (size_t)row * 512 + slot * 8;
    if (z == 2) { *(uint4*)(vhi + off) = pack8(hs); return; }
    if (z == 0) { *(uint4*)(qhi + off) = pack8(hs); *(uint4*)(qlo + off) = pack8(ls); }
    else        { *(uint4*)(khi + off) = pack8(hs); *(uint4*)(klo + off) = pack8(ls); }
}

// ---------------------------------------------------------------------------
// Kernel 0b: W prep — transpose + K-extended split layout, XOR-swizzled groups.
// ---------------------------------------------------------------------------
__global__ __launch_bounds__(256) void wprep(
    const float* __restrict__ Wq, const float* __restrict__ Wk,
    const float* __restrict__ Wv,
    short* __restrict__ Bq, short* __restrict__ Bk, short* __restrict__ Bv)
{
    __shared__ float tile[64][65];
    int z = blockIdx.z;
    const float* W = (z == 0) ? Wq : (z == 1) ? Wk : Wv;
    int k0 = blockIdx.x * 64, n0 = blockIdx.y * 64;
    int t = threadIdx.x;
    #pragma unroll
    for (int i = 0; i < 4; ++i) {
        int c = i * 256 + t, row = c >> 4, qq = c & 15;
        float4 d = *(const float4*)(W + (size_t)(k0 + row) * Dc + n0 + qq * 4);
        tile[row][qq * 4 + 0] = d.x; tile[row][qq * 4 + 1] = d.y;
        tile[row][qq * 4 + 2] = d.z; tile[row][qq * 4 + 3] = d.w;
    }
    __syncthreads();
    int n = t >> 2, ks = (t & 3) * 16;
    int nglob = n0 + n;
    short hs[16], ls[16];
    #pragma unroll
    for (int j = 0; j < 16; ++j) {
        float x = tile[ks + j][n];
        short h = f2bf(x);
        hs[j] = h;
        ls[j] = f2bf(x - bf2f(h));
    }
    int G0 = (k0 + ks) >> 3;
    int s0 = (G0 & ~7) | ((G0 ^ nglob) & 7);
    int s1 = ((G0 + 1) & ~7) | (((G0 + 1) ^ nglob) & 7);
    if (z < 2) {
        short* Bx = (z == 0) ? Bq : Bk;
        size_t rb = (size_t)nglob * 1536;
        *(uint4*)(Bx + rb + s0 * 8)        = pack8(hs);
        *(uint4*)(Bx + rb + s1 * 8)        = pack8(hs + 8);
        *(uint4*)(Bx + rb + 512 + s0 * 8)  = pack8(ls);
        *(uint4*)(Bx + rb + 512 + s1 * 8)  = pack8(ls + 8);
        *(uint4*)(Bx + rb + 1024 + s0 * 8) = pack8(hs);
        *(uint4*)(Bx + rb + 1024 + s1 * 8) = pack8(hs + 8);
    } else {
        size_t rb = (size_t)nglob * 512;
        *(uint4*)(Bv + rb + s0 * 8) = pack8(hs);
        *(uint4*)(Bv + rb + s1 * 8) = pack8(hs + 8);
    }
}

// ---------------------------------------------------------------------------
// Kernel 1: projection GEMMs, m97 structure + swizzled LDS (R15 config:
// 128x128 block, 4 waves, 64x64 per wave — the 2-phase local optimum).
// ---------------------------------------------------------------------------
__global__ __launch_bounds__(256) void gemm_mfma(
    const short* __restrict__ qhi, const short* __restrict__ qlo,
    const short* __restrict__ khi, const short* __restrict__ klo,
    const short* __restrict__ vhi,
    const short* __restrict__ Bq, const short* __restrict__ Bk,
    const short* __restrict__ Bv,
    float* __restrict__ qp, float* __restrict__ kp, float* __restrict__ vp)
{
    int z = blockIdx.z;
    const short* Ahi = (z == 0) ? qhi : (z == 1) ? khi : vhi;
    const short* Alo = (z == 0) ? qlo : (z == 1) ? klo : vhi;  // unused for z==2
    const short* Bx  = (z == 0) ? Bq  : (z == 1) ? Bk  : Bv;
    float* O = (z == 0) ? qp : (z == 1) ? kp : vp;
    const int Ktot = (z == 2) ? 512 : 1536;
    const int nseg = (z == 2) ? 1 : 3;

    __shared__ short As[128 * 64];
    __shared__ short Bs[128 * 64];

    const int t = threadIdx.x;
    const int lane = t & 63, w = t >> 6;
    const int wm = w >> 1, wn = w & 1;
    const int row0 = blockIdx.x * 128, col0 = blockIdx.y * 128;
    const int kg = lane >> 4, fr = lane & 15;
    const int sx = fr & 7;                               // read-slot XOR
    const int lrow = lane >> 3, lcol = (lane & 7) * 8;   // staging: 8 rows x 128B

    f32x4 acc[4][4];
    #pragma unroll
    for (int i = 0; i < 4; ++i)
        #pragma unroll
        for (int j = 0; j < 4; ++j)
            acc[i][j] = (f32x4){0.f, 0.f, 0.f, 0.f};

    for (int seg = 0; seg < nseg; ++seg) {
        const short* Asrc = ((seg == 2) ? Alo : Ahi)
                          + (size_t)(row0 + lrow) * 512 + lcol;
        const short* Bsrc = Bx + (size_t)(col0 + lrow) * Ktot + seg * 512 + lcol;
        for (int ks = 0; ks < 512; ks += 64) {
            __syncthreads();
            #pragma unroll
            for (int i = 0; i < 4; ++i) {
                int r = w * 32 + i * 8;
                gld_lds16(Asrc + (size_t)r * 512 + ks, &As[r * 64]);
            }
            #pragma unroll
            for (int i = 0; i < 4; ++i) {
                int r = w * 32 + i * 8;
                gld_lds16(Bsrc + (size_t)r * Ktot + ks, &Bs[r * 64]);
            }
            __syncthreads();

            #pragma unroll
            for (int kk = 0; kk < 2; ++kk) {
                const int slot = ((kk * 4 + kg) ^ sx) * 8;
                s16x8 a[4];
                #pragma unroll
                for (int mi = 0; mi < 4; ++mi)
                    a[mi] = *(const s16x8*)&As[(wm * 64 + mi * 16 + fr) * 64 + slot];
                #pragma unroll
                for (int ni = 0; ni < 4; ++ni) {
                    s16x8 b = *(const s16x8*)&Bs[(wn * 64 + ni * 16 + fr) * 64 + slot];
                    #pragma unroll
                    for (int mi = 0; mi < 4; ++mi)
                        acc[mi][ni] = __builtin_amdgcn_mfma_f32_16x16x32_bf16(a[mi], b, acc[mi][ni], 0, 0, 0);
                }
            }
        }
    }

    // epilogue: C/D layout col=lane&15, row=(lane>>4)*4+reg
    #pragma unroll
    for (int mi = 0; mi < 4; ++mi) {
        #pragma unroll
        for (int ni = 0; ni < 4; ++ni) {
            int row = row0 + wm * 64 + mi * 16 + (lane >> 4) * 4;
            int col = col0 + wn * 64 + ni * 16 + (lane & 15);
            #pragma unroll
            for (int r4 = 0; r4 < 4; ++r4)
                O[(size_t)(row + r4) * Dc + col] = acc[mi][ni][r4];
        }
    }
}

// ---------------------------------------------------------------------------
// Kernel 2: sampled scores -> m[bh, l] = max_s(dot) - sum_s(dot)/L
// GROUP-COALESCED gather + XCD-aware swizzle.
// ---------------------------------------------------------------------------
__global__ __launch_bounds__(256) void compute_m(
    const float* __restrict__ qp, const float* __restrict__ kp,
    const int* __restrict__ ksi, float* __restrict__ m_out)
{
    __shared__ float qsh[4][Ec];
    __shared__ int   jsh[4][Sc];
    int w    = threadIdx.x >> 6;
    int lane = threadIdx.x & 63;
    int xcd  = blockIdx.x & 7;
    int i    = blockIdx.x >> 3;
    int bh   = (xcd << 2) | (i >> 9);
    int l    = (i & 511) * 4 + w;
    const float* kbase = kp + (size_t)bh * LEc;

    qsh[w][lane] = qp[(size_t)bh * LEc + l * Ec + lane];
    if (lane < Sc) jsh[w][lane] = ksi[l * Sc + lane];
    __syncthreads();

    const int g = lane >> 2;
    const int c = lane & 3;

    float mx = -FLT_MAX, sm = 0.f;
    #pragma unroll
    for (int it = 0; it < 3; ++it) {
        int s = it * 16 + g;
        bool valid = (s < Sc);
        float partial = 0.f;
        if (valid) {
            int j = jsh[w][s];
            const float4* krow = (const float4*)(kbase + (size_t)j * Ec);
            #pragma unroll
            for (int ii = 0; ii < 4; ++ii) {
                float4 kv = krow[ii * 4 + c];
                float4 qv = *(const float4*)&qsh[w][ii * 16 + c * 4];
                partial += kv.x * qv.x + kv.y * qv.y + kv.z * qv.z + kv.w * qv.w;
            }
        }
        partial += __shfl_xor(partial, 1);
        partial += __shfl_xor(partial, 2);
        float vmax = valid ? partial : -FLT_MAX;
        float vsum = (valid && c == 0) ? partial : 0.f;
        #pragma unroll
        for (int o = 4; o < 64; o <<= 1) {
            vmax = fmaxf(vmax, __shfl_xor(vmax, o));
            vsum += __shfl_xor(vsum, o);
        }
        mx = fmaxf(mx, vmax);
        sm += vsum;
    }
    if (lane == 0) m_out[bh * Lc + l] = mx - sm * (1.0f / Lc);
}

// ---------------------------------------------------------------------------
// Kernel 3: top-40 selection per (bh) via RANK, thin inner loop.
// (Byte-identical to the R14/R18 version whose codegen measured ~free;
// cnt is zeroed by split_inputs instead of a separate fill dispatch.)
// ---------------------------------------------------------------------------
__global__ __launch_bounds__(256) void topk40(
    const float* __restrict__ m_in, int* __restrict__ mtop, int* __restrict__ cnt)
{
    __shared__ float vals[Lc];
    int bh = blockIdx.x >> 3, seg = blockIdx.x & 7;
    int t = threadIdx.x;
    for (int i = t; i < Lc; i += 256) vals[i] = m_in[bh * Lc + i];
    __syncthreads();
    int myi = seg * 256 + t;
    float vi = vals[myi];
    int g0 = 0, g1 = 0, g2 = 0, g3 = 0;   // strictly-greater counts
    int e0 = 0, e1 = 0, e2 = 0, e3 = 0;   // greater-or-equal counts
    const float4* v4 = (const float4*)vals;
    #pragma unroll 4
    for (int j4 = 0; j4 < Lc / 4; ++j4) {
        float4 vv = v4[j4];
        g0 += (vv.x > vi);  e0 += (vv.x >= vi);
        g1 += (vv.y > vi);  e1 += (vv.y >= vi);
        g2 += (vv.z > vi);  e2 += (vv.z >= vi);
        g3 += (vv.w > vi);  e3 += (vv.w >= vi);
    }
    int rgt = g0 + g1 + g2 + g3;
    int rge = e0 + e1 + e2 + e3;          // includes self
    bool sel;
    if (rge <= Uc)      sel = true;       // rank < 40 even counting all ties
    else if (rgt >= Uc) sel = false;
    else {                                 // tie straddles rank 40: exact path
        int req = 0;
        for (int j = 0; j < myi; ++j) req += (vals[j] == vi);
        sel = (rgt + req) < Uc;
    }
    if (sel) {
        int pos = atomicAdd(&cnt[bh], 1);
        mtop[bh * Uc + pos] = myi;
    }
}

// ---------------------------------------------------------------------------
// Kernels 4-6: chunked inclusive cumsum of vp along l, per (bh, e) column.
// ---------------------------------------------------------------------------
constexpr int CH = 64;  // chunks
constexpr int CR = 32;  // rows per chunk

__global__ __launch_bounds__(64) void cumsum_p1(
    const float* __restrict__ vp, float* __restrict__ psum)
{
    int bid = blockIdx.x;
    int e = threadIdx.x;
    int bh = bid >> 6, ch = bid & 63;
    const float* base = vp + (size_t)bh * LEc + (ch * CR) * Ec + e;
    float s = 0.f;
    #pragma unroll 8
    for (int r = 0; r < CR; ++r) s += base[r * Ec];
    psum[(size_t)bid * Ec + e] = s;
}

__global__ __launch_bounds__(64) void cumsum_p2(float* __restrict__ psum)
{
    int bh = blockIdx.x;
    int e = threadIdx.x;
    float off = 0.f;
    for (int c = 0; c < CH; ++c) {
        size_t idx = (size_t)(bh * CH + c) * Ec + e;
        float tv = psum[idx];
        psum[idx] = off;
        off += tv;
    }
}

__global__ __launch_bounds__(64) void cumsum_p3(
    const float* __restrict__ vp, const float* __restrict__ psum,
    float* __restrict__ out)
{
    int bid = blockIdx.x;
    int e = threadIdx.x;
    int bh = bid >> 6, ch = bid & 63;
    const float* base = vp  + (size_t)bh * LEc + (ch * CR) * Ec + e;
    float*       ob   = out + (size_t)bh * LEc + (ch * CR) * Ec + e;
    float run = psum[(size_t)bid * Ec + e];
    #pragma unroll 8
    for (int r = 0; r < CR; ++r) { run += base[r * Ec]; ob[r * Ec] = run; }
}

// ---------------------------------------------------------------------------
// Kernel 7a: chunked attention partials with u-reuse; fixed softmax base 0;
// balanced chunk pairing (ch, 15-ch); transposed p_t for b128 PV reads.
// ---------------------------------------------------------------------------
constexpr int ACH = 16;     // attn chunks
constexpr int AROWS = 128;  // rows per chunk

__global__ __launch_bounds__(512) void attn_partial(
    const float* __restrict__ qp, const float* __restrict__ kp,
    const float* __restrict__ vp, const int* __restrict__ mtop,
    float* __restrict__ pl, float* __restrict__ pacc)
{
    __shared__ float Kt[64][68];     // stride 68: float4-aligned rows
    __shared__ float Vt[64][68];
    __shared__ float qsh[40][64];
    __shared__ float p_t[40][68];    // p transposed: [u][row], 16B-aligned rows
    __shared__ int   lsel_sh[40];

    int half = blockIdx.x >> 8, sub = blockIdx.x & 255;
    int bh = sub & 31;
    int ch = half ? (15 - (sub >> 5)) : (sub >> 5);
    int t = threadIdx.x, w = t >> 6, lane = t & 63;
    const float* kb = kp + (size_t)bh * LEc;
    const float* vb = vp + (size_t)bh * LEc;

    if (t < Uc) lsel_sh[t] = mtop[bh * Uc + t];
    __syncthreads();
    for (int i = t; i < Uc * Ec; i += 512) {
        int u = i >> 6, e = i & 63;
        qsh[u][e] = qp[(size_t)bh * LEc + lsel_sh[u] * Ec + e];
    }

    const int u0 = w * 5;
    float acc[5]  = {0.f, 0.f, 0.f, 0.f, 0.f};
    float lreg[5] = {0.f, 0.f, 0.f, 0.f, 0.f};

    for (int tt = 0; tt < AROWS / 64; ++tt) {
        int l0 = ch * AROWS + tt * 64;
        __syncthreads();   // prev-tile reads done (and qsh written, first iter)
        #pragma unroll
        for (int i = 0; i < 2; ++i) {
            int f = i * 512 + t, row = f >> 4, cg = f & 15;
            *(float4*)&Kt[row][cg * 4] = *(const float4*)(kb + (size_t)(l0 + row) * Ec + cg * 4);
            *(float4*)&Vt[row][cg * 4] = *(const float4*)(vb + (size_t)(l0 + row) * Ec + cg * 4);
        }
        __syncthreads();

        int gl = l0 + lane;
        float4 kr[16];
        #pragma unroll
        for (int i = 0; i < 16; ++i) kr[i] = *(const float4*)&Kt[lane][i * 4];

        bool act[5];
        #pragma unroll
        for (int j = 0; j < 5; ++j) {
            int u = u0 + j, ls = lsel_sh[u];
            act[j] = (l0 <= ls);            // wave-uniform
            if (!act[j]) continue;
            float p = 0.f;
            if (gl <= ls) {
                float dot = 0.f;
                #pragma unroll
                for (int i = 0; i < 16; ++i) {
                    float4 qv = *(const float4*)&qsh[u][i * 4];   // broadcast
                    dot += kr[i].x * qv.x + kr[i].y * qv.y + kr[i].z * qv.z + kr[i].w * qv.w;
                }
                p = __expf(dot * 0.125f);   // fixed base 0
            }
            p_t[u][lane] = p;               // consecutive lanes -> conflict-free
            float ps = p;
            #pragma unroll
            for (int o = 1; o < 64; o <<= 1) ps += __shfl_xor(ps, o);
            lreg[j] += ps;
        }

        // PV: lane = e; Vt scalar reads shared across u, p via b128 broadcast.
        #pragma unroll
        for (int i = 0; i < 16; ++i) {
            float v0 = Vt[i * 4 + 0][lane];
            float v1 = Vt[i * 4 + 1][lane];
            float v2 = Vt[i * 4 + 2][lane];
            float v3 = Vt[i * 4 + 3][lane];
            #pragma unroll
            for (int j = 0; j < 5; ++j) {
                if (!act[j]) continue;
                float4 pv = *(const float4*)&p_t[u0 + j][i * 4];   // broadcast
                acc[j] += pv.x * v0 + pv.y * v1 + pv.z * v2 + pv.w * v3;
            }
        }
    }

    #pragma unroll
    for (int j = 0; j < 5; ++j) {
        size_t idx = ((size_t)bh * ACH + ch) * Uc + u0 + j;
        if (lane == 0) pl[idx] = lreg[j];
        pacc[idx * Ec + lane] = acc[j];
    }
}

// ---------------------------------------------------------------------------
// Kernel 7b: combine (plain sums — fixed base 0); write out row.
// ---------------------------------------------------------------------------
__global__ __launch_bounds__(256) void attn_combine(
    const float* __restrict__ pl, const float* __restrict__ pacc,
    const int* __restrict__ mtop, float* __restrict__ out)
{
    int wid = blockIdx.x * 4 + (threadIdx.x >> 6);
    int lane = threadIdx.x & 63;
    int bh = wid / Uc, u = wid % Uc;
    float l = 0.f, a = 0.f;
    for (int i = 0; i < ACH; ++i) {
        size_t idx = ((size_t)bh * ACH + i) * Uc + u;
        l += pl[idx];
        a += pacc[idx * Ec + lane];
    }
    int lsel = mtop[bh * Uc + u];
    out[(size_t)bh * LEc + lsel * Ec + lane] = a / l;
}

// ---------------------------------------------------------------------------
extern "C" void kernel_launch(void* const* d_in, const int* in_sizes, int n_in,
                              void* d_out, int out_size, void* d_ws, size_t ws_size,
                              hipStream_t stream)
{
    const float* q   = (const float*)d_in[0];
    const float* k   = (const float*)d_in[1];
    const float* v   = (const float*)d_in[2];
    const float* Wq  = (const float*)d_in[3];
    const float* Wk  = (const float*)d_in[4];
    const float* Wv  = (const float*)d_in[5];
    const int*   ksi = (const int*)d_in[6];
    float* out = (float*)d_out;

    // workspace layout
    float* wsf  = (float*)d_ws;
    float* qp   = wsf;                            // 4,194,304 f
    float* kp   = qp + (size_t)Mrows * Dc;        // 4,194,304 f
    float* vp   = kp + (size_t)Mrows * Dc;        // 4,194,304 f
    float* psum = vp + (size_t)Mrows * Dc;        // 131,072 f
    float* m_ws = psum + (size_t)BHc * CH * Ec;   // 65,536 f
    int*   mtop = (int*)(m_ws + (size_t)BHc * Lc);      // 1,280 i
    short* qhi = (short*)(mtop + BHc * Uc);
    short* qlo = qhi + (size_t)Mrows * Dc;
    short* khi = qlo + (size_t)Mrows * Dc;
    short* klo = khi + (size_t)Mrows * Dc;
    short* vhi = klo + (size_t)Mrows * Dc;
    short* Bq  = vhi + (size_t)Mrows * Dc;        // 512*1536
    short* Bk  = Bq + (size_t)Dc * 1536;          // 512*1536
    short* Bv  = Bk + (size_t)Dc * 1536;          // 512*512
    float* pl  = (float*)(Bv + (size_t)Dc * 512); // 32*16*40
    float* pacc = pl + (size_t)BHc * ACH * Uc;    // 32*16*40*64
    int*   cnt  = (int*)(pacc + (size_t)BHc * ACH * Uc * Ec);  // 32 ints

    split_inputs<<<3 * (Mrows * Dc / 8) / 256, 256, 0, stream>>>(
        q, k, v, qhi, qlo, khi, klo, vhi, cnt);
    wprep<<<dim3(8, 8, 3), 256, 0, stream>>>(Wq, Wk, Wv, Bq, Bk, Bv);

    dim3 g1(Mrows / 128, Dc / 128, 3);
    gemm_mfma<<<g1, 256, 0, stream>>>(qhi, qlo, khi, klo, vhi, Bq, Bk, Bv,
                                      qp, kp, vp);

    compute_m<<<(BHc * Lc) / 4, 256, 0, stream>>>(qp, kp, ksi, m_ws);

    topk40<<<BHc * 8, 256, 0, stream>>>(m_ws, mtop, cnt);

    attn_partial<<<BHc * ACH, 512, 0, stream>>>(qp, kp, vp, mtop, pl, pacc);

    cumsum_p1<<<BHc * CH, 64, 0, stream>>>(vp, psum);
    cumsum_p2<<<BHc, 64, 0, stream>>>(psum);
    cumsum_p3<<<BHc * CH, 64, 0, stream>>>(vp, psum, out);

    attn_combine<<<BHc * Uc / 4, 256, 0, stream>>>(pl, pacc, mtop, out);
}